// Round 9
// baseline (458.347 us; speedup 1.0000x reference)
//
#include <hip/hip_runtime.h>

// VanillaMHA: B=4 T=2048 D=1024 H=16 DH=64. Inputs/output fp32; internal bf16
// MFMA pipeline w/ fp32 accumulation.
// R16: LDS-BW attack on the GEMMs. Pipe arithmetic on R15 counters shows
// gemm128 is LDS-bandwidth-bound (~88% LDS-pipe busy vs 18% MFMA): read
// amplification = sum_wave(WM+WN)/(BM+BN) = 2.0x at 4x(64x64)/128^2.
// gemmB: 128x256 block, 256 thr, 4 waves of 64x128 (2Mx2N) -> 24 b128/wave/
// iter for 64 MFMA = 0.74x LDS traffic, SAME proven 1-barrier dbuf schedule
// (no new sync structure). LDS 96KB -> 1 blk/CU (4 waves); per-wave work/iter
// doubles so the 1-iter-ahead prefetch still covers HBM latency. Grids:
// gemm0 64x12=768 = 3 perfect rounds; gemm1 64x4=256 = 1 round. Staged-V
// epilogue re-derived for 256-wide bn tiles (1-2 sel==2 quadrants, staged
// into As/Bs after barriers, 16B-coalesced t-row writes).
// Carried from R15: vtr_k eliminated (V written transposed by gemm0).
// Carried from R13: fused prep_k; attn with dedicated P buffer.
// Carried from R10: 8-wave attn blocks, padded stride-68 P rows, transposed
// QK^T (S^T = mfma(K,Q)), fq-axis l-reduce, setprio around MFMA.
// Carried from R8/R7: uniform-work attn pairing (qt,15-qt), XCD bid scramble,
// exp2-domain fixed-max softmax (log2e folded into Q), XOR-swizzled staging.

typedef __attribute__((ext_vector_type(8))) short bf8v;   // 8 x bf16 (4 VGPRs)
typedef __attribute__((ext_vector_type(4))) float f4v;    // 4 x fp32

#define Tt  2048
#define Dd  1024
#define Hh  16
#define DHh 64

#if __has_builtin(__builtin_amdgcn_exp2f)
#define EXP2(x) __builtin_amdgcn_exp2f(x)
#else
#define EXP2(x) __expf((x) * 0.69314718056f)
#endif

__device__ __forceinline__ ushort f2bf(float f) {
  union { float f; unsigned v; } c; c.f = f;
  unsigned r = c.v + 0x7fffu + ((c.v >> 16) & 1u);   // RNE
  return (ushort)(r >> 16);
}
__device__ __forceinline__ ushort f2bf_rn(float f) {  // cheap round-to-nearest
  union { float f; unsigned v; } c; c.f = f;
  return (ushort)((c.v + 0x8000u) >> 16);
}
__device__ __forceinline__ f4v zero4() { f4v z; z[0]=z[1]=z[2]=z[3]=0.f; return z; }

// async global->LDS, 16B/lane; LDS base wave-uniform, data lands at
// base + laneid*16. Global address is per-lane (exploited for the swizzle).
__device__ __forceinline__ void gl_lds16(const ushort* g, ushort* l) {
  __builtin_amdgcn_global_load_lds(
      (const __attribute__((address_space(1))) unsigned*)g,
      (__attribute__((address_space(3))) unsigned*)l, 16, 0, 0);
}

// ------------------------------------ fused preprocessing (cvt x2 + LayerNorm)
// blocks [0,3072):  wqkv f32 -> bf16
// blocks [3072,4096): wo f32 -> bf16
// blocks [4096,12288): LayerNorm row (bid-4096) -> bf16
__global__ __launch_bounds__(256)
void prep_k(const float* __restrict__ wqkv, ushort* __restrict__ wqkb,
            const float* __restrict__ wo,   ushort* __restrict__ wob,
            const float* __restrict__ x, const float* __restrict__ g,
            const float* __restrict__ bta, ushort* __restrict__ xn) {
  const int bid = blockIdx.x, tid = threadIdx.x;
  if (bid < 4096) {
    const float4* src = (bid < 3072) ? (const float4*)wqkv : (const float4*)wo;
    ushort4* dst      = (bid < 3072) ? (ushort4*)wqkb : (ushort4*)wob;
    const int i = ((bid < 3072) ? bid : (bid - 3072)) * 256 + tid;
    const float4 v = src[i];
    ushort4 o;
    o.x = f2bf(v.x); o.y = f2bf(v.y); o.z = f2bf(v.z); o.w = f2bf(v.w);
    dst[i] = o;
    return;
  }
  const int row = bid - 4096;
  const float4 v = ((const float4*)(x + row * Dd))[tid];
  float s  = v.x + v.y + v.z + v.w;
  float sq = v.x*v.x + v.y*v.y + v.z*v.z + v.w*v.w;
  #pragma unroll
  for (int off = 32; off; off >>= 1) {
    s  += __shfl_down(s,  off, 64);
    sq += __shfl_down(sq, off, 64);
  }
  __shared__ float red[8];
  const int w = tid >> 6, l = tid & 63;
  if (l == 0) { red[w] = s; red[w + 4] = sq; }
  __syncthreads();
  s  = red[0] + red[1] + red[2] + red[3];
  sq = red[4] + red[5] + red[6] + red[7];
  const float mu  = s * (1.0f / Dd);
  const float var = sq * (1.0f / Dd) - mu * mu;
  const float rs  = rsqrtf(var + 1e-5f);
  const float4 gv = ((const float4*)g)[tid];
  const float4 bv = ((const float4*)bta)[tid];
  ushort4 o;
  o.x = f2bf((v.x - mu) * rs * gv.x + bv.x);
  o.y = f2bf((v.y - mu) * rs * gv.y + bv.y);
  o.z = f2bf((v.z - mu) * rs * gv.z + bv.z);
  o.w = f2bf((v.w - mu) * rs * gv.w + bv.w);
  ((ushort4*)(xn + row * Dd))[tid] = o;
}

// --------------------------------------- 128x256 GEMM  C = A * Bt^T (bf16)
// 256 thr = 4 waves (2M x 2N), wave tile 64x128 (acc[4][8], 128 VGPR).
// Same 1-barrier dbuf schedule as the proven gemm128; LDS-read traffic
// 0.74x (the measured bottleneck). LDS 96KB -> 1 block/CU.
// MODE 0: QKV projection. Q scaled by 0.125*log2(e); Q/K scattered direct
//         (b,h,t,dh); V written TRANSPOSED (b,h,dh,t) via LDS-staged
//         epilogue. MODE 1: out proj -> f32 row-major.
template<int MODE>
__global__ __launch_bounds__(256, 1)
void gemmB(const ushort* __restrict__ A, const ushort* __restrict__ Bt,
           void* __restrict__ O0v, ushort* __restrict__ O1, ushort* __restrict__ O2,
           int Kd, int nbm) {
  __shared__ ushort As[2][128 * 64];   // 32 KB
  __shared__ ushort Bs[2][256 * 64];   // 64 KB
  const int tid = threadIdx.x;
  const int l = tid & 63, w = tid >> 6, fr = l & 15, fq = l >> 4;
  const int wm = w & 1, wn = w >> 1;                    // 2M x 2N wave grid
  const int bm = blockIdx.x % nbm, bn = blockIdx.x / nbm;
  const int gr8 = l >> 3, gc8s = ((l & 7) ^ gr8) * 8;   // swizzled 16B source col
  const int sw = fr & 7;
  const int cA = (fq ^ sw) * 8, cB = ((4 + fq) ^ sw) * 8;
  const int NIT = Kd >> 6;

  f4v acc[4][8];
  #pragma unroll
  for (int m = 0; m < 4; m++)
    #pragma unroll
    for (int n = 0; n < 8; n++) acc[m][n] = zero4();

  // 12 gl_lds per wave per tile: 4 for the 128-row A panel, 8 for the
  // 256-row B panel (each call lands 8 rows x 64 k).
  auto stage = [&](int it, int bi) {
    const int k0 = it * 64;
    #pragma unroll
    for (int i = 0; i < 4; i++) {
      const int row = w * 32 + i * 8;
      gl_lds16(A + (bm * 128 + row + gr8) * Kd + k0 + gc8s, &As[bi][row * 64]);
    }
    #pragma unroll
    for (int i = 0; i < 8; i++) {
      const int row = w * 64 + i * 8;
      gl_lds16(Bt + (bn * 256 + row + gr8) * Kd + k0 + gc8s, &Bs[bi][row * 64]);
    }
  };

  stage(0, 0);
  for (int it = 0; it < NIT; ++it) {
    __syncthreads();                 // waits stage(it) (in flight during it-1's
                                     // compute) + guards buf[nxt] overwrite
    if (it + 1 < NIT) stage(it + 1, (it + 1) & 1);
    const ushort* Ab = As[it & 1];
    const ushort* Bb = Bs[it & 1];
    #pragma unroll
    for (int kk = 0; kk < 2; kk++) {
      const int cs = kk ? cB : cA;
      bf8v af[4], bf[8];
      #pragma unroll
      for (int m = 0; m < 4; m++)
        af[m] = *(const bf8v*)&Ab[(wm * 64 + m * 16 + fr) * 64 + cs];
      #pragma unroll
      for (int n = 0; n < 8; n++)
        bf[n] = *(const bf8v*)&Bb[(wn * 128 + n * 16 + fr) * 64 + cs];
      #pragma unroll
      for (int m = 0; m < 4; m++)
        #pragma unroll
        for (int n = 0; n < 8; n++)
          acc[m][n] = __builtin_amdgcn_mfma_f32_16x16x32_bf16(af[m], bf[n], acc[m][n], 0, 0, 0);
    }
  }

  // ---- direct epilogue: MODE1 full; MODE0 Q/K only (V staged below) ----
  #pragma unroll
  for (int m = 0; m < 4; m++) {
    const int grow = bm * 128 + wm * 64 + m * 16 + fq * 4;   // + r
    #pragma unroll
    for (int n = 0; n < 8; n++) {
      const int e = bn * 256 + wn * 128 + n * 16 + fr;
      #pragma unroll
      for (int r = 0; r < 4; r++) {
        const int row = grow + r;
        if (MODE == 0) {
          const int h = e / 192, inner = e % 192;
          const int sel = inner >> 6, dh = inner & 63;
          if (sel == 2) continue;                  // V goes via staged path
          const int bb = row >> 11, t = row & 2047;
          float v = acc[m][n][r];
          if (sel == 0) v *= 0.18033688f;          // (1/sqrt(64)) * log2(e)
          ushort* dst = (sel == 0) ? (ushort*)O0v : O1;
          dst[((bb * Hh + h) * Tt + t) * DHh + dh] = f2bf(v);
        } else {
          ((float*)O0v)[row * Dd + e] = acc[m][n][r];
        }
      }
    }
  }

  // ---- MODE0 staged-V epilogue: write V transposed (b,h,dh,t) ----------
  // The 256-wide bn tile has four 64-col quadrants q, sel(q) = (bn*4+q)%3;
  // 1-2 quadrants are V (sel==2), never sharing a wn (only pair (0,3)).
  // Quadrant q's acc lives in waves wn==q>>1 (both wm), n-frags (q&1)*4..+3.
  // Stage into col-major LDS [64 dh][140 t] (quadrant 0 -> As, 1 -> Bs,
  // both dead after the barrier); all 4 waves then write coalesced t-rows.
  if (MODE == 0) {
    int vqs[2]; int nv = 0;
    #pragma unroll
    for (int q = 0; q < 4; q++)
      if (((bn * 4 + q) % 3) == 2) vqs[nv++] = q;
    __syncthreads();                               // main-loop LDS reads done
    for (int i = 0; i < nv; i++) {                 // block-uniform
      const int q = vqs[i];
      ushort* Vl = (i == 0) ? &As[0][0] : &Bs[0][0];
      if (wn == (q >> 1)) {
        #pragma unroll
        for (int m = 0; m < 4; m++) {
          const int row0 = wm * 64 + m * 16 + fq * 4;
          #pragma unroll
          for (int j = 0; j < 4; j++) {
            const int n = (q & 1) * 4 + j;
            const int dh = j * 16 + fr;
            ushort4 pk;
            pk.x = f2bf(acc[m][n][0]); pk.y = f2bf(acc[m][n][1]);
            pk.z = f2bf(acc[m][n][2]); pk.w = f2bf(acc[m][n][3]);
            *(ushort4*)&Vl[dh * 140 + row0] = pk;
          }
        }
      }
    }
    __syncthreads();
    for (int i = 0; i < nv; i++) {
      const int q = vqs[i];
      const ushort* Vl = (i == 0) ? &As[0][0] : &Bs[0][0];
      const int h  = (bn * 256 + q * 64) / 192;
      const int bb = bm >> 4, t0g = (bm & 15) * 128;
      ushort* vdst = O2 + (bb * Hh + h) * (size_t)(DHh * Tt) + t0g;
      #pragma unroll
      for (int u4 = 0; u4 < 4; u4++) {
        const int u = u4 * 256 + tid;              // 1024 units
        const int dh = u >> 4, tc = (u & 15) * 8;
        const ushort4 lo = *(const ushort4*)&Vl[dh * 140 + tc];
        const ushort4 hi = *(const ushort4*)&Vl[dh * 140 + tc + 4];
        union { ushort s[8]; uint4 v; } pk;
        pk.s[0] = lo.x; pk.s[1] = lo.y; pk.s[2] = lo.z; pk.s[3] = lo.w;
        pk.s[4] = hi.x; pk.s[5] = hi.y; pk.s[6] = hi.z; pk.s[7] = hi.w;
        *(uint4*)&vdst[dh * Tt + tc] = pk.v;
      }
    }
  }
}

// ------------------------------------------------------ flash attention
// R12 structure: 512 thr = 8 waves; one (b,h) + the q-tile PAIR (qt, 15-qt)
// processed sequentially -> uniform work; grid 512 = 2 blocks/CU = 16
// waves/CU. Wave w owns q-rows w*16..+15. Double-buffered Ks/Vt, single-
// barrier pipelined k-loop. Fixed-max exp2-domain softmax (Q pre-scaled by
// 0.125*log2e). Transposed QK^T: scT = mfma(K,Q) -> lane (fq,fr) has P for
// q-row fr at k = 16*nt+4*fq+{0..3} -> packed 8B P-stores into padded
// stride-68 rows of a DEDICATED P buffer. K/V/Q staging XOR-swizzled.
__global__ __launch_bounds__(512)
void attn_k(const ushort* __restrict__ Qb, const ushort* __restrict__ Kb,
            const ushort* __restrict__ Vtg, ushort* __restrict__ ctx) {
  __shared__ ushort QS[128 * 64];                    // 16 KB: Q staging (stride 64)
  __shared__ ushort Pb[128 * 68];                    // 17 KB: P (stride 68)
  __shared__ ushort Ks[2][64 * 64], Vt[2][64 * 64];  // 16 KB each (dbuf)
  const int tid = threadIdx.x;
  const int l = tid & 63, w = tid >> 6, fr = l & 15, fq = l >> 4;
  const int bid = blockIdx.x;
  // XCD scramble: blocks of one head share bid&7 -> same XCD under
  // round-robin dispatch; per-XCD KV working set = 8 heads ~= 4MB ~= L2.
  const int hb = (bid & 7) * 8 + (bid >> 6);       // b*16+h
  const int u  = (bid >> 3) & 7;                   // pair index 0..7
  const int h  = hb & 15, b = hb >> 4;
  const int headbase = hb * Tt * DHh;
  const int gr8 = l >> 3, gc8s = ((l & 7) ^ gr8) * 8;
  const int sw = fr & 7;
  const int cA = (fq ^ sw) * 8, cB = ((4 + fq) ^ sw) * 8;

  auto stageKV = [&](int kt, int bi) {
    const int row = w * 8;                         // 8 waves x 8 rows = 64
    gl_lds16(Kb  + headbase + (kt * 64 + row + gr8) * DHh + gc8s, &Ks[bi][row * 64]);
    gl_lds16(Vtg + headbase + (row + gr8) * Tt + kt * 64 + gc8s, &Vt[bi][row * 64]);
  };

  for (int half = 0; half < 2; ++half) {
    const int qt = half ? (15 - u) : u;
    const int qrow0w = qt * 128 + w * 16;          // wave's first q-row

    // seam guard: full drain (vmcnt+lgkm+barrier) before re-staging Q/KV
    // over buffers still being read by other waves in the previous half.
    if (half) __syncthreads();

    #pragma unroll
    for (int i = 0; i < 2; i++) {
      const int row = w * 16 + i * 8;
      gl_lds16(Qb + headbase + (qt * 128 + row + gr8) * DHh + gc8s, &QS[row * 64]);
    }
    stageKV(0, 0);
    __syncthreads();                               // Q + tile0 visible

    bf8v aq[2];
    aq[0] = *(const bf8v*)&QS[(w * 16 + fr) * 64 + cA];
    aq[1] = *(const bf8v*)&QS[(w * 16 + fr) * 64 + cB];
    __asm__ __volatile__("" ::: "memory");

    f4v o[4];
    #pragma unroll
    for (int n = 0; n < 4; n++) o[n] = zero4();
    float lsum = 0.f;                              // per-lane: q-row fr

    const int ktmax = 2 * qt + 1;
    for (int kt = 0; kt <= ktmax; ++kt) {
      if (kt) __syncthreads();       // waits stage(kt) (flew during kt-1's
                                     // compute) + guards buf[nxt] overwrite
      if (kt < ktmax) stageKV(kt + 1, (kt + 1) & 1);
      const ushort* K_ = Ks[kt & 1];
      const ushort* V_ = Vt[kt & 1];

      if (kt * 64 <= qrow0w + 15) {                // wave-uniform causal skip
        // S'^T = K (Q*log2e/8)^T : lane (fq,fr) -> q-row fr, k = 16nt+4fq+r
        f4v scT[4];
        #pragma unroll
        for (int n = 0; n < 4; n++) scT[n] = zero4();
        __builtin_amdgcn_s_setprio(1);
        #pragma unroll
        for (int nt = 0; nt < 4; nt++) {
          const bf8v k0 = *(const bf8v*)&K_[(nt * 16 + fr) * 64 + cA];
          const bf8v k1 = *(const bf8v*)&K_[(nt * 16 + fr) * 64 + cB];
          scT[nt] = __builtin_amdgcn_mfma_f32_16x16x32_bf16(k0, aq[0], scT[nt], 0, 0, 0);
          scT[nt] = __builtin_amdgcn_mfma_f32_16x16x32_bf16(k1, aq[1], scT[nt], 0, 0, 0);
        }
        __builtin_amdgcn_s_setprio(0);

        if (kt * 64 + 63 > qrow0w) {               // diagonal tiles only
          const int q0 = qrow0w + fr;
          #pragma unroll
          for (int nt = 0; nt < 4; nt++) {
            const int kc0 = kt * 64 + nt * 16 + fq * 4;
            #pragma unroll
            for (int r = 0; r < 4; r++)
              if (kc0 + r > q0) scT[nt][r] = -1e30f;
          }
        }

        // P = exp2(s') -> packed 8B stores, padded stride-68 rows (own buf).
        {
          const int prow = w * 16 + fr;
          ushort* pbase = &Pb[prow * 68 + fq * 4];
          #pragma unroll
          for (int nt = 0; nt < 4; nt++) {
            const float p0 = EXP2(scT[nt][0]), p1 = EXP2(scT[nt][1]);
            const float p2 = EXP2(scT[nt][2]), p3 = EXP2(scT[nt][3]);
            ushort4 pk;
            pk.x = f2bf_rn(p0); pk.y = f2bf_rn(p1);
            pk.z = f2bf_rn(p2); pk.w = f2bf_rn(p3);
            *(ushort4*)(pbase + nt * 16) = pk;
            lsum += (p0 + p1) + (p2 + p3);
          }
        }

        __asm__ __volatile__("" ::: "memory");   // order per-wave P stores before loads

        // O += P V
        __builtin_amdgcn_s_setprio(1);
        #pragma unroll
        for (int s = 0; s < 2; s++) {
          const bf8v ap = *(const bf8v*)&Pb[(w * 16 + fr) * 68 + s * 32 + fq * 8];
          #pragma unroll
          for (int nt = 0; nt < 4; nt++) {
            const bf8v bv2 = *(const bf8v*)&V_[(nt * 16 + fr) * 64 + (s ? cB : cA)];
            o[nt] = __builtin_amdgcn_mfma_f32_16x16x32_bf16(ap, bv2, o[nt], 0, 0, 0);
          }
        }
        __builtin_amdgcn_s_setprio(0);
      }
    }

    // finalize l: reduce over fq groups (lanes xor 16,32 share q-row fr),
    // then broadcast to the lanes that own that q-row in the o-layout.
    float t = lsum;
    t += __shfl_xor(t, 16, 64);
    t += __shfl_xor(t, 32, 64);
    const float inv = 1.0f / t;
    #pragma unroll
    for (int r = 0; r < 4; r++) {
      // o[nt][r] belongs to q-row fq*4+r; its inv lives in lane 20*fq+r.
      const float iv = __shfl(inv, 20 * fq + r, 64);
      const int rowg = b * Tt + qt * 128 + w * 16 + fq * 4 + r;
      #pragma unroll
      for (int nt = 0; nt < 4; nt++)
        ctx[rowg * Dd + h * DHh + nt * 16 + fr] = f2bf(o[nt][r] * iv);
    }
  }
}

// ---------------------------------------------------------------- launcher
extern "C" void kernel_launch(void* const* d_in, const int* in_sizes, int n_in,
                              void* d_out, int out_size, void* d_ws, size_t ws_size,
                              hipStream_t stream) {
  const float* x    = (const float*)d_in[0];
  const float* g    = (const float*)d_in[1];
  const float* bta  = (const float*)d_in[2];
  const float* wqkv = (const float*)d_in[3];
  const float* wo   = (const float*)d_in[4];

  const int NROW = 4 * Tt;                 // 8192
  const int NQ   = 4 * Hh * Tt * DHh;      // 8388608
  ushort* xn   = (ushort*)d_ws;
  ushort* Qb   = xn + NROW * Dd;
  ushort* Kb   = Qb + NQ;
  ushort* Vb   = Kb + NQ;                  // holds V TRANSPOSED (b,h,dh,t)
  ushort* ctx  = Vb + NQ;
  ushort* wqkb = ctx + NROW * Dd;
  ushort* wob  = wqkb + 3 * Dd * Dd;

  prep_k<<<3072 + 1024 + NROW, 256, 0, stream>>>(wqkv, wqkb, wo, wob, x, g, bta, xn);
  gemmB<0><<<64 * 12, 256, 0, stream>>>(xn, wqkb, Qb, Kb, Vb, Dd, 64);
  attn_k<<<4 * Hh * (Tt / 128) / 2, 512, 0, stream>>>(Qb, Kb, Vb, ctx);
  gemmB<1><<<64 * 4, 256, 0, stream>>>(ctx, wob, (void*)d_out, nullptr, nullptr, Dd, 64);
}

// Round 10
// 257.935 us; speedup vs baseline: 1.7770x; 1.7770x over previous
//
#include <hip/hip_runtime.h>

// VanillaMHA: B=4 T=2048 D=1024 H=16 DH=64. Inputs/output fp32; internal bf16
// MFMA pipeline w/ fp32 accumulation.
// R17: fix R16's rule-#20 violation. R16's staged-V epilogue indexed acc with
// a RUNTIME quadrant (acc[m][(q&1)*4+j], q from vqs[i]) -> compiler demoted
// the whole accumulator to scratch (VGPR_Count 136, WRITE_SIZE 1.7GB/dispatch,
// 289us). Fix: static #pragma unroll q=0..3 with runtime CONDITION but
// compile-time indices; static buffer map q<2->As, q>=2->Bs (V-quadrant pairs
// are only (0,3) -> no collision). This re-runs the R16 LDS-BW experiment
// validly: 128x256 block, 4 waves of 64x128 (2Mx2N) = 0.74x LDS traffic vs
// gemm128, same proven 1-barrier dbuf schedule. LDS 96KB -> 1 blk/CU.
// Carried from R15: vtr_k eliminated (V written transposed by gemm0).
// Carried from R13: fused prep_k; attn with dedicated P buffer.
// Carried from R10: 8-wave attn blocks, padded stride-68 P rows, transposed
// QK^T (S^T = mfma(K,Q)), fq-axis l-reduce, setprio around MFMA.
// Carried from R8/R7: uniform-work attn pairing (qt,15-qt), XCD bid scramble,
// exp2-domain fixed-max softmax (log2e folded into Q), XOR-swizzled staging.

typedef __attribute__((ext_vector_type(8))) short bf8v;   // 8 x bf16 (4 VGPRs)
typedef __attribute__((ext_vector_type(4))) float f4v;    // 4 x fp32

#define Tt  2048
#define Dd  1024
#define Hh  16
#define DHh 64

#if __has_builtin(__builtin_amdgcn_exp2f)
#define EXP2(x) __builtin_amdgcn_exp2f(x)
#else
#define EXP2(x) __expf((x) * 0.69314718056f)
#endif

__device__ __forceinline__ ushort f2bf(float f) {
  union { float f; unsigned v; } c; c.f = f;
  unsigned r = c.v + 0x7fffu + ((c.v >> 16) & 1u);   // RNE
  return (ushort)(r >> 16);
}
__device__ __forceinline__ ushort f2bf_rn(float f) {  // cheap round-to-nearest
  union { float f; unsigned v; } c; c.f = f;
  return (ushort)((c.v + 0x8000u) >> 16);
}
__device__ __forceinline__ f4v zero4() { f4v z; z[0]=z[1]=z[2]=z[3]=0.f; return z; }

// async global->LDS, 16B/lane; LDS base wave-uniform, data lands at
// base + laneid*16. Global address is per-lane (exploited for the swizzle).
__device__ __forceinline__ void gl_lds16(const ushort* g, ushort* l) {
  __builtin_amdgcn_global_load_lds(
      (const __attribute__((address_space(1))) unsigned*)g,
      (__attribute__((address_space(3))) unsigned*)l, 16, 0, 0);
}

// ------------------------------------ fused preprocessing (cvt x2 + LayerNorm)
// blocks [0,3072):  wqkv f32 -> bf16
// blocks [3072,4096): wo f32 -> bf16
// blocks [4096,12288): LayerNorm row (bid-4096) -> bf16
__global__ __launch_bounds__(256)
void prep_k(const float* __restrict__ wqkv, ushort* __restrict__ wqkb,
            const float* __restrict__ wo,   ushort* __restrict__ wob,
            const float* __restrict__ x, const float* __restrict__ g,
            const float* __restrict__ bta, ushort* __restrict__ xn) {
  const int bid = blockIdx.x, tid = threadIdx.x;
  if (bid < 4096) {
    const float4* src = (bid < 3072) ? (const float4*)wqkv : (const float4*)wo;
    ushort4* dst      = (bid < 3072) ? (ushort4*)wqkb : (ushort4*)wob;
    const int i = ((bid < 3072) ? bid : (bid - 3072)) * 256 + tid;
    const float4 v = src[i];
    ushort4 o;
    o.x = f2bf(v.x); o.y = f2bf(v.y); o.z = f2bf(v.z); o.w = f2bf(v.w);
    dst[i] = o;
    return;
  }
  const int row = bid - 4096;
  const float4 v = ((const float4*)(x + row * Dd))[tid];
  float s  = v.x + v.y + v.z + v.w;
  float sq = v.x*v.x + v.y*v.y + v.z*v.z + v.w*v.w;
  #pragma unroll
  for (int off = 32; off; off >>= 1) {
    s  += __shfl_down(s,  off, 64);
    sq += __shfl_down(sq, off, 64);
  }
  __shared__ float red[8];
  const int w = tid >> 6, l = tid & 63;
  if (l == 0) { red[w] = s; red[w + 4] = sq; }
  __syncthreads();
  s  = red[0] + red[1] + red[2] + red[3];
  sq = red[4] + red[5] + red[6] + red[7];
  const float mu  = s * (1.0f / Dd);
  const float var = sq * (1.0f / Dd) - mu * mu;
  const float rs  = rsqrtf(var + 1e-5f);
  const float4 gv = ((const float4*)g)[tid];
  const float4 bv = ((const float4*)bta)[tid];
  ushort4 o;
  o.x = f2bf((v.x - mu) * rs * gv.x + bv.x);
  o.y = f2bf((v.y - mu) * rs * gv.y + bv.y);
  o.z = f2bf((v.z - mu) * rs * gv.z + bv.z);
  o.w = f2bf((v.w - mu) * rs * gv.w + bv.w);
  ((ushort4*)(xn + row * Dd))[tid] = o;
}

// --------------------------------------- 128x256 GEMM  C = A * Bt^T (bf16)
// 256 thr = 4 waves (2M x 2N), wave tile 64x128 (acc[4][8], 128 VGPR).
// Same 1-barrier dbuf schedule as the proven gemm128; LDS-read traffic
// 0.74x (the measured bottleneck). LDS 96KB -> 1 block/CU.
// MODE 0: QKV projection. Q scaled by 0.125*log2(e); Q/K scattered direct
//         (b,h,t,dh); V written TRANSPOSED (b,h,dh,t) via LDS-staged
//         epilogue (ALL indices into acc compile-time static — rule #20).
// MODE 1: out proj -> f32 row-major.
template<int MODE>
__global__ __launch_bounds__(256, 1)
void gemmB(const ushort* __restrict__ A, const ushort* __restrict__ Bt,
           void* __restrict__ O0v, ushort* __restrict__ O1, ushort* __restrict__ O2,
           int Kd, int nbm) {
  __shared__ ushort As[2][128 * 64];   // 32 KB
  __shared__ ushort Bs[2][256 * 64];   // 64 KB
  const int tid = threadIdx.x;
  const int l = tid & 63, w = tid >> 6, fr = l & 15, fq = l >> 4;
  const int wm = w & 1, wn = w >> 1;                    // 2M x 2N wave grid
  const int bm = blockIdx.x % nbm, bn = blockIdx.x / nbm;
  const int gr8 = l >> 3, gc8s = ((l & 7) ^ gr8) * 8;   // swizzled 16B source col
  const int sw = fr & 7;
  const int cA = (fq ^ sw) * 8, cB = ((4 + fq) ^ sw) * 8;
  const int NIT = Kd >> 6;

  f4v acc[4][8];
  #pragma unroll
  for (int m = 0; m < 4; m++)
    #pragma unroll
    for (int n = 0; n < 8; n++) acc[m][n] = zero4();

  // 12 gl_lds per wave per tile: 4 for the 128-row A panel, 8 for the
  // 256-row B panel (each call lands 8 rows x 64 k).
  auto stage = [&](int it, int bi) {
    const int k0 = it * 64;
    #pragma unroll
    for (int i = 0; i < 4; i++) {
      const int row = w * 32 + i * 8;
      gl_lds16(A + (bm * 128 + row + gr8) * Kd + k0 + gc8s, &As[bi][row * 64]);
    }
    #pragma unroll
    for (int i = 0; i < 8; i++) {
      const int row = w * 64 + i * 8;
      gl_lds16(Bt + (bn * 256 + row + gr8) * Kd + k0 + gc8s, &Bs[bi][row * 64]);
    }
  };

  stage(0, 0);
  for (int it = 0; it < NIT; ++it) {
    __syncthreads();                 // waits stage(it) (in flight during it-1's
                                     // compute) + guards buf[nxt] overwrite
    if (it + 1 < NIT) stage(it + 1, (it + 1) & 1);
    const ushort* Ab = As[it & 1];
    const ushort* Bb = Bs[it & 1];
    #pragma unroll
    for (int kk = 0; kk < 2; kk++) {
      const int cs = kk ? cB : cA;
      bf8v af[4], bf[8];
      #pragma unroll
      for (int m = 0; m < 4; m++)
        af[m] = *(const bf8v*)&Ab[(wm * 64 + m * 16 + fr) * 64 + cs];
      #pragma unroll
      for (int n = 0; n < 8; n++)
        bf[n] = *(const bf8v*)&Bb[(wn * 128 + n * 16 + fr) * 64 + cs];
      #pragma unroll
      for (int m = 0; m < 4; m++)
        #pragma unroll
        for (int n = 0; n < 8; n++)
          acc[m][n] = __builtin_amdgcn_mfma_f32_16x16x32_bf16(af[m], bf[n], acc[m][n], 0, 0, 0);
    }
  }

  // ---- direct epilogue: MODE1 full; MODE0 Q/K only (V staged below) ----
  #pragma unroll
  for (int m = 0; m < 4; m++) {
    const int grow = bm * 128 + wm * 64 + m * 16 + fq * 4;   // + r
    #pragma unroll
    for (int n = 0; n < 8; n++) {
      const int e = bn * 256 + wn * 128 + n * 16 + fr;
      #pragma unroll
      for (int r = 0; r < 4; r++) {
        const int row = grow + r;
        if (MODE == 0) {
          const int h = e / 192, inner = e % 192;
          const int sel = inner >> 6, dh = inner & 63;
          if (sel == 2) continue;                  // V goes via staged path
          const int bb = row >> 11, t = row & 2047;
          float v = acc[m][n][r];
          if (sel == 0) v *= 0.18033688f;          // (1/sqrt(64)) * log2(e)
          ushort* dst = (sel == 0) ? (ushort*)O0v : O1;
          dst[((bb * Hh + h) * Tt + t) * DHh + dh] = f2bf(v);
        } else {
          ((float*)O0v)[row * Dd + e] = acc[m][n][r];
        }
      }
    }
  }

  // ---- MODE0 staged-V epilogue: write V transposed (b,h,dh,t) ----------
  // The 256-wide bn tile has four 64-col quadrants q, sel(q) = (bn*4+q)%3;
  // 1-2 quadrants are V (sel==2), only pair (0,3) can co-occur. Quadrant
  // q's acc lives in waves wn==q>>1 (both wm), n-frags (q&1)*4..+3. STATIC
  // q loop (rule #20: all acc indices compile-time); static buffer map
  // q<2 -> As, q>=2 -> Bs (pair (0,3) -> no collision). Stage col-major
  // [64 dh][140 t], then all 4 waves write 16B-coalesced t-rows.
  if (MODE == 0) {
    __syncthreads();                               // main-loop LDS reads done
    #pragma unroll
    for (int q = 0; q < 4; q++) {
      if (((bn * 4 + q) % 3) == 2 && wn == (q >> 1)) {   // runtime cond, static q
        ushort* Vl = (q < 2) ? &As[0][0] : &Bs[0][0];
        #pragma unroll
        for (int m = 0; m < 4; m++) {
          const int row0 = wm * 64 + m * 16 + fq * 4;
          #pragma unroll
          for (int j = 0; j < 4; j++) {
            const int dh = j * 16 + fr;
            ushort4 pk;
            pk.x = f2bf(acc[m][(q & 1) * 4 + j][0]);
            pk.y = f2bf(acc[m][(q & 1) * 4 + j][1]);
            pk.z = f2bf(acc[m][(q & 1) * 4 + j][2]);
            pk.w = f2bf(acc[m][(q & 1) * 4 + j][3]);
            *(ushort4*)&Vl[dh * 140 + row0] = pk;
          }
        }
      }
    }
    __syncthreads();
    #pragma unroll
    for (int q = 0; q < 4; q++) {
      if (((bn * 4 + q) % 3) == 2) {               // block-uniform branch
        const ushort* Vl = (q < 2) ? &As[0][0] : &Bs[0][0];
        const int h  = (bn * 256 + q * 64) / 192;
        const int bb = bm >> 4, t0g = (bm & 15) * 128;
        ushort* vdst = O2 + (bb * Hh + h) * (size_t)(DHh * Tt) + t0g;
        #pragma unroll
        for (int u4 = 0; u4 < 4; u4++) {
          const int u = u4 * 256 + tid;            // 1024 units
          const int dh = u >> 4, tc = (u & 15) * 8;
          const ushort4 lo = *(const ushort4*)&Vl[dh * 140 + tc];
          const ushort4 hi = *(const ushort4*)&Vl[dh * 140 + tc + 4];
          union { ushort s[8]; uint4 v; } pk;
          pk.s[0] = lo.x; pk.s[1] = lo.y; pk.s[2] = lo.z; pk.s[3] = lo.w;
          pk.s[4] = hi.x; pk.s[5] = hi.y; pk.s[6] = hi.z; pk.s[7] = hi.w;
          *(uint4*)&vdst[dh * Tt + tc] = pk.v;
        }
      }
    }
  }
}

// ------------------------------------------------------ flash attention
// R12 structure: 512 thr = 8 waves; one (b,h) + the q-tile PAIR (qt, 15-qt)
// processed sequentially -> uniform work; grid 512 = 2 blocks/CU = 16
// waves/CU. Wave w owns q-rows w*16..+15. Double-buffered Ks/Vt, single-
// barrier pipelined k-loop. Fixed-max exp2-domain softmax (Q pre-scaled by
// 0.125*log2e). Transposed QK^T: scT = mfma(K,Q) -> lane (fq,fr) has P for
// q-row fr at k = 16*nt+4*fq+{0..3} -> packed 8B P-stores into padded
// stride-68 rows of a DEDICATED P buffer. K/V/Q staging XOR-swizzled.
__global__ __launch_bounds__(512)
void attn_k(const ushort* __restrict__ Qb, const ushort* __restrict__ Kb,
            const ushort* __restrict__ Vtg, ushort* __restrict__ ctx) {
  __shared__ ushort QS[128 * 64];                    // 16 KB: Q staging (stride 64)
  __shared__ ushort Pb[128 * 68];                    // 17 KB: P (stride 68)
  __shared__ ushort Ks[2][64 * 64], Vt[2][64 * 64];  // 16 KB each (dbuf)
  const int tid = threadIdx.x;
  const int l = tid & 63, w = tid >> 6, fr = l & 15, fq = l >> 4;
  const int bid = blockIdx.x;
  // XCD scramble: blocks of one head share bid&7 -> same XCD under
  // round-robin dispatch; per-XCD KV working set = 8 heads ~= 4MB ~= L2.
  const int hb = (bid & 7) * 8 + (bid >> 6);       // b*16+h
  const int u  = (bid >> 3) & 7;                   // pair index 0..7
  const int h  = hb & 15, b = hb >> 4;
  const int headbase = hb * Tt * DHh;
  const int gr8 = l >> 3, gc8s = ((l & 7) ^ gr8) * 8;
  const int sw = fr & 7;
  const int cA = (fq ^ sw) * 8, cB = ((4 + fq) ^ sw) * 8;

  auto stageKV = [&](int kt, int bi) {
    const int row = w * 8;                         // 8 waves x 8 rows = 64
    gl_lds16(Kb  + headbase + (kt * 64 + row + gr8) * DHh + gc8s, &Ks[bi][row * 64]);
    gl_lds16(Vtg + headbase + (row + gr8) * Tt + kt * 64 + gc8s, &Vt[bi][row * 64]);
  };

  for (int half = 0; half < 2; ++half) {
    const int qt = half ? (15 - u) : u;
    const int qrow0w = qt * 128 + w * 16;          // wave's first q-row

    // seam guard: full drain (vmcnt+lgkm+barrier) before re-staging Q/KV
    // over buffers still being read by other waves in the previous half.
    if (half) __syncthreads();

    #pragma unroll
    for (int i = 0; i < 2; i++) {
      const int row = w * 16 + i * 8;
      gl_lds16(Qb + headbase + (qt * 128 + row + gr8) * DHh + gc8s, &QS[row * 64]);
    }
    stageKV(0, 0);
    __syncthreads();                               // Q + tile0 visible

    bf8v aq[2];
    aq[0] = *(const bf8v*)&QS[(w * 16 + fr) * 64 + cA];
    aq[1] = *(const bf8v*)&QS[(w * 16 + fr) * 64 + cB];
    __asm__ __volatile__("" ::: "memory");

    f4v o[4];
    #pragma unroll
    for (int n = 0; n < 4; n++) o[n] = zero4();
    float lsum = 0.f;                              // per-lane: q-row fr

    const int ktmax = 2 * qt + 1;
    for (int kt = 0; kt <= ktmax; ++kt) {
      if (kt) __syncthreads();       // waits stage(kt) (flew during kt-1's
                                     // compute) + guards buf[nxt] overwrite
      if (kt < ktmax) stageKV(kt + 1, (kt + 1) & 1);
      const ushort* K_ = Ks[kt & 1];
      const ushort* V_ = Vt[kt & 1];

      if (kt * 64 <= qrow0w + 15) {                // wave-uniform causal skip
        // S'^T = K (Q*log2e/8)^T : lane (fq,fr) -> q-row fr, k = 16nt+4fq+r
        f4v scT[4];
        #pragma unroll
        for (int n = 0; n < 4; n++) scT[n] = zero4();
        __builtin_amdgcn_s_setprio(1);
        #pragma unroll
        for (int nt = 0; nt < 4; nt++) {
          const bf8v k0 = *(const bf8v*)&K_[(nt * 16 + fr) * 64 + cA];
          const bf8v k1 = *(const bf8v*)&K_[(nt * 16 + fr) * 64 + cB];
          scT[nt] = __builtin_amdgcn_mfma_f32_16x16x32_bf16(k0, aq[0], scT[nt], 0, 0, 0);
          scT[nt] = __builtin_amdgcn_mfma_f32_16x16x32_bf16(k1, aq[1], scT[nt], 0, 0, 0);
        }
        __builtin_amdgcn_s_setprio(0);

        if (kt * 64 + 63 > qrow0w) {               // diagonal tiles only
          const int q0 = qrow0w + fr;
          #pragma unroll
          for (int nt = 0; nt < 4; nt++) {
            const int kc0 = kt * 64 + nt * 16 + fq * 4;
            #pragma unroll
            for (int r = 0; r < 4; r++)
              if (kc0 + r > q0) scT[nt][r] = -1e30f;
          }
        }

        // P = exp2(s') -> packed 8B stores, padded stride-68 rows (own buf).
        {
          const int prow = w * 16 + fr;
          ushort* pbase = &Pb[prow * 68 + fq * 4];
          #pragma unroll
          for (int nt = 0; nt < 4; nt++) {
            const float p0 = EXP2(scT[nt][0]), p1 = EXP2(scT[nt][1]);
            const float p2 = EXP2(scT[nt][2]), p3 = EXP2(scT[nt][3]);
            ushort4 pk;
            pk.x = f2bf_rn(p0); pk.y = f2bf_rn(p1);
            pk.z = f2bf_rn(p2); pk.w = f2bf_rn(p3);
            *(ushort4*)(pbase + nt * 16) = pk;
            lsum += (p0 + p1) + (p2 + p3);
          }
        }

        __asm__ __volatile__("" ::: "memory");   // order per-wave P stores before loads

        // O += P V
        __builtin_amdgcn_s_setprio(1);
        #pragma unroll
        for (int s = 0; s < 2; s++) {
          const bf8v ap = *(const bf8v*)&Pb[(w * 16 + fr) * 68 + s * 32 + fq * 8];
          #pragma unroll
          for (int nt = 0; nt < 4; nt++) {
            const bf8v bv2 = *(const bf8v*)&V_[(nt * 16 + fr) * 64 + (s ? cB : cA)];
            o[nt] = __builtin_amdgcn_mfma_f32_16x16x32_bf16(ap, bv2, o[nt], 0, 0, 0);
          }
        }
        __builtin_amdgcn_s_setprio(0);
      }
    }

    // finalize l: reduce over fq groups (lanes xor 16,32 share q-row fr),
    // then broadcast to the lanes that own that q-row in the o-layout.
    float t = lsum;
    t += __shfl_xor(t, 16, 64);
    t += __shfl_xor(t, 32, 64);
    const float inv = 1.0f / t;
    #pragma unroll
    for (int r = 0; r < 4; r++) {
      // o[nt][r] belongs to q-row fq*4+r; its inv lives in lane 20*fq+r.
      const float iv = __shfl(inv, 20 * fq + r, 64);
      const int rowg = b * Tt + qt * 128 + w * 16 + fq * 4 + r;
      #pragma unroll
      for (int nt = 0; nt < 4; nt++)
        ctx[rowg * Dd + h * DHh + nt * 16 + fr] = f2bf(o[nt][r] * iv);
    }
  }
}

// ---------------------------------------------------------------- launcher
extern "C" void kernel_launch(void* const* d_in, const int* in_sizes, int n_in,
                              void* d_out, int out_size, void* d_ws, size_t ws_size,
                              hipStream_t stream) {
  const float* x    = (const float*)d_in[0];
  const float* g    = (const float*)d_in[1];
  const float* bta  = (const float*)d_in[2];
  const float* wqkv = (const float*)d_in[3];
  const float* wo   = (const float*)d_in[4];

  const int NROW = 4 * Tt;                 // 8192
  const int NQ   = 4 * Hh * Tt * DHh;      // 8388608
  ushort* xn   = (ushort*)d_ws;
  ushort* Qb   = xn + NROW * Dd;
  ushort* Kb   = Qb + NQ;
  ushort* Vb   = Kb + NQ;                  // holds V TRANSPOSED (b,h,dh,t)
  ushort* ctx  = Vb + NQ;
  ushort* wqkb = ctx + NROW * Dd;
  ushort* wob  = wqkb + 3 * Dd * Dd;

  prep_k<<<3072 + 1024 + NROW, 256, 0, stream>>>(wqkv, wqkb, wo, wob, x, g, bta, xn);
  gemmB<0><<<64 * 12, 256, 0, stream>>>(xn, wqkb, Qb, Kb, Vb, Dd, 64);
  attn_k<<<4 * Hh * (Tt / 128) / 2, 512, 0, stream>>>(Qb, Kb, Vb, ctx);
  gemmB<1><<<64 * 4, 256, 0, stream>>>(ctx, wob, (void*)d_out, nullptr, nullptr, Dd, 64);
}

// Round 11
// 240.605 us; speedup vs baseline: 1.9050x; 1.0720x over previous
//
#include <hip/hip_runtime.h>

// VanillaMHA: B=4 T=2048 D=1024 H=16 DH=64. Inputs/output fp32; internal bf16
// MFMA pipeline w/ fp32 accumulation.
// R18: GEMM exploration closed (R11/R14/R16-17 all lost to gemm128's 763 TF;
// fat-wave R17 proved TLP>=2 waves/SIMD is a prerequisite for LDS-pipe
// saturation). GEMMs reverted to R15's proven gemm128 (+staged-V epilogue).
// NEW (isolated): attn occupancy 2->3 blocks/CU.
//  - P folded into the dead QS buffer at stride 64 with XOR block swizzle
//    (b64 block b=4nt+fq stored at b^((fr&7)<<1); writer/reader lanes share
//    fr -> consistent; strictly wave-private rows w*16..+15 -> no cross-wave
//    alias, unlike R10's stride-68-over-64 overlap). Removes Pb: LDS 48 KB.
//  - __launch_bounds__(512,6) caps VGPR ~84 -> 6 waves/SIMD -> 3 blocks/CU.
//    Grid 512 <= 3*256 -> ALL attn blocks co-resident, zero dispatch rounds.
// Carried from R15: vtr_k eliminated (V written transposed by gemm0 epilogue).
// Carried from R13: fused prep_k.
// Carried from R10: 8-wave attn blocks, transposed QK^T (S^T = mfma(K,Q)),
// fq-axis l-reduce, setprio around MFMA.
// Carried from R8/R7: uniform-work attn pairing (qt,15-qt), XCD bid scramble,
// exp2-domain fixed-max softmax (log2e folded into Q), XOR-swizzled staging.

typedef __attribute__((ext_vector_type(8))) short bf8v;   // 8 x bf16 (4 VGPRs)
typedef __attribute__((ext_vector_type(4))) float f4v;    // 4 x fp32

#define Tt  2048
#define Dd  1024
#define Hh  16
#define DHh 64

#if __has_builtin(__builtin_amdgcn_exp2f)
#define EXP2(x) __builtin_amdgcn_exp2f(x)
#else
#define EXP2(x) __expf((x) * 0.69314718056f)
#endif

__device__ __forceinline__ ushort f2bf(float f) {
  union { float f; unsigned v; } c; c.f = f;
  unsigned r = c.v + 0x7fffu + ((c.v >> 16) & 1u);   // RNE
  return (ushort)(r >> 16);
}
__device__ __forceinline__ ushort f2bf_rn(float f) {  // cheap round-to-nearest
  union { float f; unsigned v; } c; c.f = f;
  return (ushort)((c.v + 0x8000u) >> 16);
}
__device__ __forceinline__ f4v zero4() { f4v z; z[0]=z[1]=z[2]=z[3]=0.f; return z; }

// async global->LDS, 16B/lane; LDS base wave-uniform, data lands at
// base + laneid*16. Global address is per-lane (exploited for the swizzle).
__device__ __forceinline__ void gl_lds16(const ushort* g, ushort* l) {
  __builtin_amdgcn_global_load_lds(
      (const __attribute__((address_space(1))) unsigned*)g,
      (__attribute__((address_space(3))) unsigned*)l, 16, 0, 0);
}

// ------------------------------------ fused preprocessing (cvt x2 + LayerNorm)
// blocks [0,3072):  wqkv f32 -> bf16
// blocks [3072,4096): wo f32 -> bf16
// blocks [4096,12288): LayerNorm row (bid-4096) -> bf16
__global__ __launch_bounds__(256)
void prep_k(const float* __restrict__ wqkv, ushort* __restrict__ wqkb,
            const float* __restrict__ wo,   ushort* __restrict__ wob,
            const float* __restrict__ x, const float* __restrict__ g,
            const float* __restrict__ bta, ushort* __restrict__ xn) {
  const int bid = blockIdx.x, tid = threadIdx.x;
  if (bid < 4096) {
    const float4* src = (bid < 3072) ? (const float4*)wqkv : (const float4*)wo;
    ushort4* dst      = (bid < 3072) ? (ushort4*)wqkb : (ushort4*)wob;
    const int i = ((bid < 3072) ? bid : (bid - 3072)) * 256 + tid;
    const float4 v = src[i];
    ushort4 o;
    o.x = f2bf(v.x); o.y = f2bf(v.y); o.z = f2bf(v.z); o.w = f2bf(v.w);
    dst[i] = o;
    return;
  }
  const int row = bid - 4096;
  const float4 v = ((const float4*)(x + row * Dd))[tid];
  float s  = v.x + v.y + v.z + v.w;
  float sq = v.x*v.x + v.y*v.y + v.z*v.z + v.w*v.w;
  #pragma unroll
  for (int off = 32; off; off >>= 1) {
    s  += __shfl_down(s,  off, 64);
    sq += __shfl_down(sq, off, 64);
  }
  __shared__ float red[8];
  const int w = tid >> 6, l = tid & 63;
  if (l == 0) { red[w] = s; red[w + 4] = sq; }
  __syncthreads();
  s  = red[0] + red[1] + red[2] + red[3];
  sq = red[4] + red[5] + red[6] + red[7];
  const float mu  = s * (1.0f / Dd);
  const float var = sq * (1.0f / Dd) - mu * mu;
  const float rs  = rsqrtf(var + 1e-5f);
  const float4 gv = ((const float4*)g)[tid];
  const float4 bv = ((const float4*)bta)[tid];
  ushort4 o;
  o.x = f2bf((v.x - mu) * rs * gv.x + bv.x);
  o.y = f2bf((v.y - mu) * rs * gv.y + bv.y);
  o.z = f2bf((v.z - mu) * rs * gv.z + bv.z);
  o.w = f2bf((v.w - mu) * rs * gv.w + bv.w);
  ((ushort4*)(xn + row * Dd))[tid] = o;
}

// --------------------------------------- 128x128 GEMM  C = A * Bt^T (bf16)
// Pipelined: dbuf LDS, one barrier/iter, prefetch issued right after barrier.
// MODE 0: QKV projection. Q scaled by 0.125*log2(e); Q/K scattered direct
//         (b,h,t,dh); V written TRANSPOSED (b,h,dh,t) via LDS-staged
//         epilogue. MODE 1: out proj -> f32 row-major.
template<int MODE>
__global__ __launch_bounds__(256)
void gemm128(const ushort* __restrict__ A, const ushort* __restrict__ Bt,
             void* __restrict__ O0v, ushort* __restrict__ O1, ushort* __restrict__ O2,
             int Kd, int nbm) {
  __shared__ ushort As[2][128 * 64], Bs[2][128 * 64];   // 64 KB
  const int tid = threadIdx.x;
  const int l = tid & 63, w = tid >> 6, fr = l & 15, fq = l >> 4;
  const int wm = w & 1, wn = w >> 1;
  const int bm = blockIdx.x % nbm, bn = blockIdx.x / nbm;
  const int gr8 = l >> 3, gc8s = ((l & 7) ^ gr8) * 8;   // swizzled 16B source col
  const int sw = fr & 7;
  const int cA = (fq ^ sw) * 8, cB = ((4 + fq) ^ sw) * 8;
  const int NIT = Kd >> 6;

  f4v acc[4][4];
  #pragma unroll
  for (int m = 0; m < 4; m++)
    #pragma unroll
    for (int n = 0; n < 4; n++) acc[m][n] = zero4();

  auto stage = [&](int it, int bi) {
    const int k0 = it * 64;
    #pragma unroll
    for (int i = 0; i < 4; i++) {
      const int row = w * 32 + i * 8;
      gl_lds16(A  + (bm * 128 + row + gr8) * Kd + k0 + gc8s, &As[bi][row * 64]);
      gl_lds16(Bt + (bn * 128 + row + gr8) * Kd + k0 + gc8s, &Bs[bi][row * 64]);
    }
  };

  stage(0, 0);
  for (int it = 0; it < NIT; ++it) {
    __syncthreads();                 // waits stage(it) (in flight during it-1's
                                     // compute) + guards buf[nxt] overwrite
    if (it + 1 < NIT) stage(it + 1, (it + 1) & 1);
    const ushort* Ab = As[it & 1];
    const ushort* Bb = Bs[it & 1];
    #pragma unroll
    for (int kk = 0; kk < 2; kk++) {
      const int cs = kk ? cB : cA;
      bf8v af[4], bf[4];
      #pragma unroll
      for (int m = 0; m < 4; m++)
        af[m] = *(const bf8v*)&Ab[(wm * 64 + m * 16 + fr) * 64 + cs];
      #pragma unroll
      for (int n = 0; n < 4; n++)
        bf[n] = *(const bf8v*)&Bb[(wn * 64 + n * 16 + fr) * 64 + cs];
      #pragma unroll
      for (int m = 0; m < 4; m++)
        #pragma unroll
        for (int n = 0; n < 4; n++)
          acc[m][n] = __builtin_amdgcn_mfma_f32_16x16x32_bf16(af[m], bf[n], acc[m][n], 0, 0, 0);
    }
  }

  // ---- direct epilogue: MODE1 full; MODE0 Q/K only (V staged below) ----
  #pragma unroll
  for (int m = 0; m < 4; m++) {
    const int grow = bm * 128 + wm * 64 + m * 16 + fq * 4;   // + r
    #pragma unroll
    for (int n = 0; n < 4; n++) {
      const int e = bn * 128 + wn * 64 + n * 16 + fr;
      #pragma unroll
      for (int r = 0; r < 4; r++) {
        const int row = grow + r;
        if (MODE == 0) {
          const int h = e / 192, inner = e % 192;
          const int sel = inner >> 6, dh = inner & 63;
          if (sel == 2) continue;                  // V goes via staged path
          const int bb = row >> 11, t = row & 2047;
          float v = acc[m][n][r];
          if (sel == 0) v *= 0.18033688f;          // (1/sqrt(64)) * log2(e)
          ushort* dst = (sel == 0) ? (ushort*)O0v : O1;
          dst[((bb * Hh + h) * Tt + t) * DHh + dh] = f2bf(v);
        } else {
          ((float*)O0v)[row * Dd + e] = acc[m][n][r];
        }
      }
    }
  }

  // ---- MODE0 staged-V epilogue: write V transposed (b,h,dh,t) ----------
  // In a 128-wide bn tile the two 64-col runs are sel-uniform; the V-run
  // (if any) maps onto waves wn==vrun. Those 2 waves stage acc into a
  // col-major LDS tile Vl[dh][140] (aliased over As after a barrier); all 8
  // waves then write 16B-coalesced t-rows.
  if (MODE == 0) {
    const int bnm3 = bn % 3;
    if (bnm3 != 0) {                               // block-uniform branch
      const int vrun = (bnm3 == 1) ? 0 : 1;
      ushort* Vl = &As[0][0];                      // 64*140 ushorts <= As
      __syncthreads();                             // main-loop LDS reads done
      if (wn == vrun) {
        #pragma unroll
        for (int m = 0; m < 4; m++) {
          const int row0 = wm * 64 + m * 16 + fq * 4;
          #pragma unroll
          for (int n = 0; n < 4; n++) {
            const int col = n * 16 + fr;           // = dh
            ushort4 pk;
            pk.x = f2bf(acc[m][n][0]); pk.y = f2bf(acc[m][n][1]);
            pk.z = f2bf(acc[m][n][2]); pk.w = f2bf(acc[m][n][3]);
            *(ushort4*)&Vl[col * 140 + row0] = pk;
          }
        }
      }
      __syncthreads();
      const int evr = bn * 128 + vrun * 64;
      const int hq  = evr / 192;
      const int bb  = bm >> 4, t0g = (bm & 15) * 128;
      ushort* vdst = O2 + (bb * Hh + hq) * (size_t)(DHh * Tt) + t0g;
      #pragma unroll
      for (int i = 0; i < 4; i++) {
        const int u = i * 256 + tid;               // 1024 units
        const int dh = u >> 4, tc = (u & 15) * 8;
        const ushort4 lo = *(const ushort4*)&Vl[dh * 140 + tc];
        const ushort4 hi = *(const ushort4*)&Vl[dh * 140 + tc + 4];
        union { ushort s[8]; uint4 v; } pk;
        pk.s[0] = lo.x; pk.s[1] = lo.y; pk.s[2] = lo.z; pk.s[3] = lo.w;
        pk.s[4] = hi.x; pk.s[5] = hi.y; pk.s[6] = hi.z; pk.s[7] = hi.w;
        *(uint4*)&vdst[dh * Tt + tc] = pk.v;
      }
    }
  }
}

// ------------------------------------------------------ flash attention
// 512 thr = 8 waves; one (b,h) + the q-tile PAIR (qt, 15-qt) processed
// sequentially -> uniform work; grid 512, 3 blocks/CU (all co-resident).
// Wave w owns q-rows w*16..+15. Double-buffered Ks/Vt, single-barrier
// pipelined k-loop. Fixed-max exp2-domain softmax (Q pre-scaled by
// 0.125*log2e). Transposed QK^T: scT = mfma(K,Q) -> lane (fq,fr) has P for
// q-row fr at k = 16*nt+4*fq+{0..3}. P is stored into the DEAD QS buffer
// (Q already in aq registers) at stride 64 with XOR block swizzle:
// b64 block b=4nt+fq stored at b^((fr&7)<<1). Writer lanes (all fq', fixed
// fr) and the reader lane of row fr share fr -> consistent mapping; rows are
// wave-private (w*16..+15) -> no cross-wave alias. Stores 2-way/bank (free),
// b128 reads at the 8-access floor. LDS total 48 KB; launch_bounds(512,6)
// caps VGPR for 6 waves/SIMD = 3 blocks/CU.
__global__ __launch_bounds__(512, 6)
void attn_k(const ushort* __restrict__ Qb, const ushort* __restrict__ Kb,
            const ushort* __restrict__ Vtg, ushort* __restrict__ ctx) {
  __shared__ ushort QS[128 * 64];                    // 16 KB: Q staging, then P
  __shared__ ushort Ks[2][64 * 64], Vt[2][64 * 64];  // 16 KB each (dbuf)
  const int tid = threadIdx.x;
  const int l = tid & 63, w = tid >> 6, fr = l & 15, fq = l >> 4;
  const int bid = blockIdx.x;
  // XCD scramble: blocks of one head share bid&7 -> same XCD under
  // round-robin dispatch; per-XCD KV working set = 8 heads ~= 4MB ~= L2.
  const int hb = (bid & 7) * 8 + (bid >> 6);       // b*16+h
  const int u  = (bid >> 3) & 7;                   // pair index 0..7
  const int h  = hb & 15, b = hb >> 4;
  const int headbase = hb * Tt * DHh;
  const int gr8 = l >> 3, gc8s = ((l & 7) ^ gr8) * 8;
  const int sw = fr & 7;
  const int cA = (fq ^ sw) * 8, cB = ((4 + fq) ^ sw) * 8;
  const int e2 = (fr & 7) << 1;                    // P block swizzle

  auto stageKV = [&](int kt, int bi) {
    const int row = w * 8;                         // 8 waves x 8 rows = 64
    gl_lds16(Kb  + headbase + (kt * 64 + row + gr8) * DHh + gc8s, &Ks[bi][row * 64]);
    gl_lds16(Vtg + headbase + (row + gr8) * Tt + kt * 64 + gc8s, &Vt[bi][row * 64]);
  };

  for (int half = 0; half < 2; ++half) {
    const int qt = half ? (15 - u) : u;
    const int qrow0w = qt * 128 + w * 16;          // wave's first q-row

    // seam guard: full drain (vmcnt+lgkm+barrier) before re-staging Q/KV
    // over buffers still being read by other waves in the previous half.
    if (half) __syncthreads();

    #pragma unroll
    for (int i = 0; i < 2; i++) {
      const int row = w * 16 + i * 8;
      gl_lds16(Qb + headbase + (qt * 128 + row + gr8) * DHh + gc8s, &QS[row * 64]);
    }
    stageKV(0, 0);
    __syncthreads();                               // Q + tile0 visible

    bf8v aq[2];
    aq[0] = *(const bf8v*)&QS[(w * 16 + fr) * 64 + cA];
    aq[1] = *(const bf8v*)&QS[(w * 16 + fr) * 64 + cB];
    __asm__ __volatile__("" ::: "memory");         // Q reads before P writes

    f4v o[4];
    #pragma unroll
    for (int n = 0; n < 4; n++) o[n] = zero4();
    float lsum = 0.f;                              // per-lane: q-row fr

    const int ktmax = 2 * qt + 1;
    for (int kt = 0; kt <= ktmax; ++kt) {
      if (kt) __syncthreads();       // waits stage(kt) (flew during kt-1's
                                     // compute) + guards buf[nxt] overwrite
      if (kt < ktmax) stageKV(kt + 1, (kt + 1) & 1);
      const ushort* K_ = Ks[kt & 1];
      const ushort* V_ = Vt[kt & 1];

      if (kt * 64 <= qrow0w + 15) {                // wave-uniform causal skip
        // S'^T = K (Q*log2e/8)^T : lane (fq,fr) -> q-row fr, k = 16nt+4fq+r
        f4v scT[4];
        #pragma unroll
        for (int n = 0; n < 4; n++) scT[n] = zero4();
        __builtin_amdgcn_s_setprio(1);
        #pragma unroll
        for (int nt = 0; nt < 4; nt++) {
          const bf8v k0 = *(const bf8v*)&K_[(nt * 16 + fr) * 64 + cA];
          const bf8v k1 = *(const bf8v*)&K_[(nt * 16 + fr) * 64 + cB];
          scT[nt] = __builtin_amdgcn_mfma_f32_16x16x32_bf16(k0, aq[0], scT[nt], 0, 0, 0);
          scT[nt] = __builtin_amdgcn_mfma_f32_16x16x32_bf16(k1, aq[1], scT[nt], 0, 0, 0);
        }
        __builtin_amdgcn_s_setprio(0);

        if (kt * 64 + 63 > qrow0w) {               // diagonal tiles only
          const int q0 = qrow0w + fr;
          #pragma unroll
          for (int nt = 0; nt < 4; nt++) {
            const int kc0 = kt * 64 + nt * 16 + fq * 4;
            #pragma unroll
            for (int r = 0; r < 4; r++)
              if (kc0 + r > q0) scT[nt][r] = -1e30f;
          }
        }

        // P = exp2(s') -> packed 8B stores into QS rows (wave-private,
        // stride 64, block index XOR-swizzled by e2).
        {
          ushort* pbase = &QS[(w * 16 + fr) * 64];
          #pragma unroll
          for (int nt = 0; nt < 4; nt++) {
            const float p0 = EXP2(scT[nt][0]), p1 = EXP2(scT[nt][1]);
            const float p2 = EXP2(scT[nt][2]), p3 = EXP2(scT[nt][3]);
            ushort4 pk;
            pk.x = f2bf_rn(p0); pk.y = f2bf_rn(p1);
            pk.z = f2bf_rn(p2); pk.w = f2bf_rn(p3);
            *(ushort4*)(pbase + (((4 * nt + fq) ^ e2) << 2)) = pk;
            lsum += (p0 + p1) + (p2 + p3);
          }
        }

        __asm__ __volatile__("" ::: "memory");   // order per-wave P stores before loads

        // O += P V   (P read back b128: logical blocks 8s+2fq, +1 -> swizzled
        // positions are adjacent since e2 has bit0=0)
        __builtin_amdgcn_s_setprio(1);
        #pragma unroll
        for (int s = 0; s < 2; s++) {
          const bf8v ap = *(const bf8v*)&QS[(w * 16 + fr) * 64 + (((8 * s + 2 * fq) ^ e2) << 2)];
          #pragma unroll
          for (int nt = 0; nt < 4; nt++) {
            const bf8v bv2 = *(const bf8v*)&V_[(nt * 16 + fr) * 64 + (s ? cB : cA)];
            o[nt] = __builtin_amdgcn_mfma_f32_16x16x32_bf16(ap, bv2, o[nt], 0, 0, 0);
          }
        }
        __builtin_amdgcn_s_setprio(0);
      }
    }

    // finalize l: reduce over fq groups (lanes xor 16,32 share q-row fr),
    // then broadcast to the lanes that own that q-row in the o-layout.
    float t = lsum;
    t += __shfl_xor(t, 16, 64);
    t += __shfl_xor(t, 32, 64);
    const float inv = 1.0f / t;
    #pragma unroll
    for (int r = 0; r < 4; r++) {
      // o[nt][r] belongs to q-row fq*4+r; its inv lives in lane 20*fq+r.
      const float iv = __shfl(inv, 20 * fq + r, 64);
      const int rowg = b * Tt + qt * 128 + w * 16 + fq * 4 + r;
      #pragma unroll
      for (int nt = 0; nt < 4; nt++)
        ctx[rowg * Dd + h * DHh + nt * 16 + fr] = f2bf(o[nt][r] * iv);
    }
  }
}

// ---------------------------------------------------------------- launcher
extern "C" void kernel_launch(void* const* d_in, const int* in_sizes, int n_in,
                              void* d_out, int out_size, void* d_ws, size_t ws_size,
                              hipStream_t stream) {
  const float* x    = (const float*)d_in[0];
  const float* g    = (const float*)d_in[1];
  const float* bta  = (const float*)d_in[2];
  const float* wqkv = (const float*)d_in[3];
  const float* wo   = (const float*)d_in[4];

  const int NROW = 4 * Tt;                 // 8192
  const int NQ   = 4 * Hh * Tt * DHh;      // 8388608
  ushort* xn   = (ushort*)d_ws;
  ushort* Qb   = xn + NROW * Dd;
  ushort* Kb   = Qb + NQ;
  ushort* Vb   = Kb + NQ;                  // holds V TRANSPOSED (b,h,dh,t)
  ushort* ctx  = Vb + NQ;
  ushort* wqkb = ctx + NROW * Dd;
  ushort* wob  = wqkb + 3 * Dd * Dd;

  prep_k<<<3072 + 1024 + NROW, 256, 0, stream>>>(wqkv, wqkb, wo, wob, x, g, bta, xn);
  gemm128<0><<<64 * 24, 256, 0, stream>>>(xn, wqkb, Qb, Kb, Vb, Dd, 64);
  attn_k<<<4 * Hh * (Tt / 128) / 2, 512, 0, stream>>>(Qb, Kb, Vb, ctx);
  gemm128<1><<<64 * 8, 256, 0, stream>>>(ctx, wob, (void*)d_out, nullptr, nullptr, Dd, 64);
}